// Round 1
// baseline (1861.505 us; speedup 1.0000x reference)
//
#include <hip/hip_runtime.h>
#include <hip/hip_bf16.h>
#include <stdint.h>

// ---- problem dims (fixed by setup_inputs) ----
#define DIM   4096
#define HID   11008
#define MTOK  4096              // B*S = 2*2048
#define NELW  (HID * DIM)       // 45,088,768 elements per weight matrix

typedef __bf16 bf16x8 __attribute__((ext_vector_type(8)));
typedef float  f32x4  __attribute__((ext_vector_type(4)));
using gptr_t = const __attribute__((address_space(1))) void*;
using lptr_t = __attribute__((address_space(3))) void*;

__device__ __forceinline__ float bf2f(unsigned short u) {
    unsigned int t = ((unsigned int)u) << 16;
    float f; __builtin_memcpy(&f, &t, 4); return f;
}
__device__ __forceinline__ unsigned short f2bf(float f) {   // RNE
    unsigned int x; __builtin_memcpy(&x, &f, 4);
    x += 0x7fffu + ((x >> 16) & 1u);
    return (unsigned short)(x >> 16);
}

__device__ __constant__ float NF4_TAB[16] = {
    -1.0f, -0.6961928009986877f, -0.5250730514526367f, -0.39491748809814453f,
    -0.28444138169288635f, -0.18477343022823334f, -0.09105003625154495f, 0.0f,
    0.07958029955625534f, 0.16093020141124725f, 0.24611230194568634f,
    0.33791524171829224f, 0.44070982933044434f, 0.5626170039176941f,
    0.6989939212799072f, 1.0f};

// NF4 dequant: 8 codes/thread; table lookup via __shfl from lanes 0..15.
// BLOCK=64 divides the 8-element group, so one absmax per thread.
__global__ __launch_bounds__(256) void dequant_nf4_k(
    const int* __restrict__ codes, const float* __restrict__ absmax,
    unsigned short* __restrict__ out)
{
    long base = ((long)blockIdx.x * 256 + threadIdx.x) * 8;
    float tv = NF4_TAB[threadIdx.x & 15];           // lanes 0..15 hold the table
    int4 c0 = *(const int4*)(codes + base);
    int4 c1 = *(const int4*)(codes + base + 4);
    float s = absmax[base >> 6];
    union { uint4 q; unsigned short u[8]; } o;
    o.u[0] = f2bf(__shfl(tv, c0.x) * s);
    o.u[1] = f2bf(__shfl(tv, c0.y) * s);
    o.u[2] = f2bf(__shfl(tv, c0.z) * s);
    o.u[3] = f2bf(__shfl(tv, c0.w) * s);
    o.u[4] = f2bf(__shfl(tv, c1.x) * s);
    o.u[5] = f2bf(__shfl(tv, c1.y) * s);
    o.u[6] = f2bf(__shfl(tv, c1.z) * s);
    o.u[7] = f2bf(__shfl(tv, c1.w) * s);
    *(uint4*)(out + base) = o.q;
}

__global__ __launch_bounds__(256) void cast_f32_bf16_k(
    const float* __restrict__ in, unsigned short* __restrict__ out)
{
    long base = ((long)blockIdx.x * 256 + threadIdx.x) * 8;
    float4 a = *(const float4*)(in + base);
    float4 b = *(const float4*)(in + base + 4);
    union { uint4 q; unsigned short u[8]; } o;
    o.u[0] = f2bf(a.x); o.u[1] = f2bf(a.y); o.u[2] = f2bf(a.z); o.u[3] = f2bf(a.w);
    o.u[4] = f2bf(b.x); o.u[5] = f2bf(b.y); o.u[6] = f2bf(b.z); o.u[7] = f2bf(b.w);
    *(uint4*)(out + base) = o.q;
}

// h = bf16( silu(h1) * h3 ), elementwise, in-place safe (out may alias h1)
__global__ __launch_bounds__(256) void swiglu_k(
    const unsigned short* __restrict__ h1, const unsigned short* __restrict__ h3,
    unsigned short* __restrict__ out)
{
    long base = ((long)blockIdx.x * 256 + threadIdx.x) * 8;
    union { uint4 q; unsigned short u[8]; } a, b, o;
    a.q = *(const uint4*)(h1 + base);
    b.q = *(const uint4*)(h3 + base);
    #pragma unroll
    for (int j = 0; j < 8; ++j) {
        float x = bf2f(a.u[j]);
        float g = x / (1.0f + __expf(-x));      // silu, fp32
        o.u[j] = f2bf(g * bf2f(b.u[j]));
    }
    *(uint4*)(out + base) = o.q;
}

// C[m,n] = sum_k A[m,k]*B[n,k].  A:[M,K] bf16, B:[N,K] bf16, row-major.
// m97 structure: 128x128 tile, BK=64, 4 waves (2x2), mfma_f32_16x16x32_bf16,
// global_load_lds width=16 staging (linear LDS, wave-uniform dest), 2-barrier loop.
// Requires M%128==0, N%128==0, K%64==0, grid%8==0 (all hold here).
template<int OUTBF16>
__global__ __launch_bounds__(256) void gemm_bt_k(
    const unsigned short* __restrict__ A, const unsigned short* __restrict__ B,
    void* __restrict__ Cout, int M, int N, int K)
{
    __shared__ __align__(16) unsigned short As[128 * 64];
    __shared__ __align__(16) unsigned short Bs[128 * 64];

    const int tid = threadIdx.x;
    const int w = tid >> 6, lane = tid & 63;
    const int nbm = M >> 7, nbn = N >> 7;
    const int cpx = (nbm * nbn) >> 3;            // grid % 8 == 0 -> bijective
    int swz = ((int)blockIdx.x & 7) * cpx + ((int)blockIdx.x >> 3);
    const int bm = swz / nbn, bn = swz % nbn;

    const long ldK = K;
    // staging: flat chunk = j*256 + tid ; row = j*32 + (tid>>3), col = (tid&7)*8
    const unsigned short* ga = A + ((long)(bm * 128 + (tid >> 3))) * ldK + (tid & 7) * 8;
    const unsigned short* gb = B + ((long)(bn * 128 + (tid >> 3))) * ldK + (tid & 7) * 8;

    const int wr = (w >> 1) * 64, wc = (w & 1) * 64;   // wave's 64x64 sub-tile
    const int lrow = lane & 15;
    const int lkb = (lane >> 4) << 3;                  // k-offset 0/8/16/24

    f32x4 acc[4][4];
    #pragma unroll
    for (int m = 0; m < 4; ++m) {
        #pragma unroll
        for (int n = 0; n < 4; ++n) acc[m][n] = f32x4{0.f, 0.f, 0.f, 0.f};
    }

    const int nkt = K >> 6;
    for (int kt = 0; kt < nkt; ++kt) {
        #pragma unroll
        for (int j = 0; j < 4; ++j) {
            __builtin_amdgcn_global_load_lds((gptr_t)(ga + (long)j * 32 * ldK),
                (lptr_t)((char*)As + j * 4096 + w * 1024), 16, 0, 0);
            __builtin_amdgcn_global_load_lds((gptr_t)(gb + (long)j * 32 * ldK),
                (lptr_t)((char*)Bs + j * 4096 + w * 1024), 16, 0, 0);
        }
        ga += 64; gb += 64;
        __syncthreads();                                // drains vmcnt -> LDS ready
        #pragma unroll
        for (int ks = 0; ks < 2; ++ks) {
            bf16x8 fa[4], fb[4];
            #pragma unroll
            for (int m = 0; m < 4; ++m)
                fa[m] = *(const bf16x8*)(&As[(wr + m * 16 + lrow) * 64 + ks * 32 + lkb]);
            #pragma unroll
            for (int n = 0; n < 4; ++n)
                fb[n] = *(const bf16x8*)(&Bs[(wc + n * 16 + lrow) * 64 + ks * 32 + lkb]);
            #pragma unroll
            for (int m = 0; m < 4; ++m) {
                #pragma unroll
                for (int n = 0; n < 4; ++n)
                    acc[m][n] = __builtin_amdgcn_mfma_f32_16x16x32_bf16(
                        fa[m], fb[n], acc[m][n], 0, 0, 0);
            }
        }
        __syncthreads();                                // protect LDS overwrite
    }

    // C/D layout (m89-verified): col = lane&15, row = (lane>>4)*4 + reg
    const int grow = bm * 128 + wr + (lane >> 4) * 4;
    const int gcol = bn * 128 + wc + lrow;
    if (OUTBF16) {
        unsigned short* C = (unsigned short*)Cout;
        #pragma unroll
        for (int m = 0; m < 4; ++m)
            #pragma unroll
            for (int n = 0; n < 4; ++n)
                #pragma unroll
                for (int r = 0; r < 4; ++r)
                    C[(long)(grow + m * 16 + r) * N + gcol + n * 16] = f2bf(acc[m][n][r]);
    } else {
        float* C = (float*)Cout;
        #pragma unroll
        for (int m = 0; m < 4; ++m)
            #pragma unroll
            for (int n = 0; n < 4; ++n)
                #pragma unroll
                for (int r = 0; r < 4; ++r)
                    C[(long)(grow + m * 16 + r) * N + gcol + n * 16] = acc[m][n][r];
    }
}

// ---- workspace layout (bytes) ----
//  [0)          W1 bf16 (90,177,536)  -- later reused for W2
//  [90177536)   W3 bf16 (90,177,536)
//  [180355072)  x  bf16 (33,554,432)
//  [213909504)  h1 bf16 (90,177,536)  -- swiglu output written in-place
//  [304087040)  h3 bf16 (90,177,536)
//  total 394,264,576
#define WS_NEEDED 394264576UL

extern "C" void kernel_launch(void* const* d_in, const int* in_sizes, int n_in,
                              void* d_out, int out_size, void* d_ws, size_t ws_size,
                              hipStream_t stream) {
    const float* x   = (const float*)d_in[0];
    const int*   w1c = (const int*)d_in[1];
    const float* w1a = (const float*)d_in[2];
    const int*   w2c = (const int*)d_in[3];
    const float* w2a = (const float*)d_in[4];
    const int*   w3c = (const int*)d_in[5];
    const float* w3a = (const float*)d_in[6];

    if (ws_size < WS_NEEDED) return;   // fail loudly via validation

    char* ws = (char*)d_ws;
    unsigned short* W1 = (unsigned short*)(ws);              // also W2 later
    unsigned short* W3 = (unsigned short*)(ws + 90177536);
    unsigned short* Xb = (unsigned short*)(ws + 180355072);
    unsigned short* H1 = (unsigned short*)(ws + 213909504);
    unsigned short* H3 = (unsigned short*)(ws + 304087040);

    const int wblk = NELW / (8 * 256);          // 22016
    dequant_nf4_k<<<wblk, 256, 0, stream>>>(w1c, w1a, W1);
    dequant_nf4_k<<<wblk, 256, 0, stream>>>(w3c, w3a, W3);
    cast_f32_bf16_k<<<(MTOK * DIM) / (8 * 256), 256, 0, stream>>>(x, Xb);

    // h1 = x @ W1^T, h3 = x @ W3^T   [4096 x 11008]
    gemm_bt_k<1><<<(MTOK / 128) * (HID / 128), 256, 0, stream>>>(Xb, W1, H1, MTOK, HID, DIM);
    gemm_bt_k<1><<<(MTOK / 128) * (HID / 128), 256, 0, stream>>>(Xb, W3, H3, MTOK, HID, DIM);

    // h = silu(h1) * h3, in-place into H1
    swiglu_k<<<wblk, 256, 0, stream>>>(H1, H3, H1);

    // W2 into W1's buffer (GEMM1 already retired on this stream)
    dequant_nf4_k<<<wblk, 256, 0, stream>>>(w2c, w2a, W1);

    // out = h @ W2^T  [4096 x 4096], fp32 output
    gemm_bt_k<0><<<(MTOK / 128) * (DIM / 128), 256, 0, stream>>>(H1, W1, (float*)d_out, MTOK, DIM, HID);
}

// Round 2
// 1585.747 us; speedup vs baseline: 1.1739x; 1.1739x over previous
//
#include <hip/hip_runtime.h>
#include <hip/hip_bf16.h>
#include <stdint.h>

// ---- problem dims (fixed by setup_inputs) ----
#define DIM   4096
#define HID   11008
#define MTOK  4096              // B*S = 2*2048
#define NELW  (HID * DIM)       // 45,088,768 elements per weight matrix

typedef __bf16 bf16x8 __attribute__((ext_vector_type(8)));
typedef float  f32x4  __attribute__((ext_vector_type(4)));
using gptr_t = const __attribute__((address_space(1))) void*;
using lptr_t = __attribute__((address_space(3))) void*;

__device__ __forceinline__ float bf2f(unsigned short u) {
    unsigned int t = ((unsigned int)u) << 16;
    float f; __builtin_memcpy(&f, &t, 4); return f;
}
__device__ __forceinline__ unsigned short f2bf(float f) {   // RNE
    unsigned int x; __builtin_memcpy(&x, &f, 4);
    x += 0x7fffu + ((x >> 16) & 1u);
    return (unsigned short)(x >> 16);
}

__device__ __constant__ float NF4_TAB[16] = {
    -1.0f, -0.6961928009986877f, -0.5250730514526367f, -0.39491748809814453f,
    -0.28444138169288635f, -0.18477343022823334f, -0.09105003625154495f, 0.0f,
    0.07958029955625534f, 0.16093020141124725f, 0.24611230194568634f,
    0.33791524171829224f, 0.44070982933044434f, 0.5626170039176941f,
    0.6989939212799072f, 1.0f};

// NF4 dequant: 8 codes/thread; table lookup via __shfl from lanes 0..15.
__global__ __launch_bounds__(256) void dequant_nf4_k(
    const int* __restrict__ codes, const float* __restrict__ absmax,
    unsigned short* __restrict__ out)
{
    long base = ((long)blockIdx.x * 256 + threadIdx.x) * 8;
    float tv = NF4_TAB[threadIdx.x & 15];           // lanes 0..15 hold the table
    int4 c0 = *(const int4*)(codes + base);
    int4 c1 = *(const int4*)(codes + base + 4);
    float s = absmax[base >> 6];
    union { uint4 q; unsigned short u[8]; } o;
    o.u[0] = f2bf(__shfl(tv, c0.x) * s);
    o.u[1] = f2bf(__shfl(tv, c0.y) * s);
    o.u[2] = f2bf(__shfl(tv, c0.z) * s);
    o.u[3] = f2bf(__shfl(tv, c0.w) * s);
    o.u[4] = f2bf(__shfl(tv, c1.x) * s);
    o.u[5] = f2bf(__shfl(tv, c1.y) * s);
    o.u[6] = f2bf(__shfl(tv, c1.z) * s);
    o.u[7] = f2bf(__shfl(tv, c1.w) * s);
    *(uint4*)(out + base) = o.q;
}

__global__ __launch_bounds__(256) void cast_f32_bf16_k(
    const float* __restrict__ in, unsigned short* __restrict__ out)
{
    long base = ((long)blockIdx.x * 256 + threadIdx.x) * 8;
    float4 a = *(const float4*)(in + base);
    float4 b = *(const float4*)(in + base + 4);
    union { uint4 q; unsigned short u[8]; } o;
    o.u[0] = f2bf(a.x); o.u[1] = f2bf(a.y); o.u[2] = f2bf(a.z); o.u[3] = f2bf(a.w);
    o.u[4] = f2bf(b.x); o.u[5] = f2bf(b.y); o.u[6] = f2bf(b.z); o.u[7] = f2bf(b.w);
    *(uint4*)(out + base) = o.q;
}

// h = bf16( silu(h1) * h3 ), elementwise, in-place safe (out may alias h1)
__global__ __launch_bounds__(256) void swiglu_k(
    const unsigned short* __restrict__ h1, const unsigned short* __restrict__ h3,
    unsigned short* __restrict__ out)
{
    long base = ((long)blockIdx.x * 256 + threadIdx.x) * 8;
    union { uint4 q; unsigned short u[8]; } a, b, o;
    a.q = *(const uint4*)(h1 + base);
    b.q = *(const uint4*)(h3 + base);
    #pragma unroll
    for (int j = 0; j < 8; ++j) {
        float x = bf2f(a.u[j]);
        float g = x / (1.0f + __expf(-x));      // silu, fp32
        o.u[j] = f2bf(g * bf2f(b.u[j]));
    }
    *(uint4*)(out + base) = o.q;
}

// C[m,n] = sum_k A[m,k]*B[n,k].  A:[M,K] bf16, B:[N,K] bf16, row-major.
// m97 structure (128x128 tile, BK=64, 4 waves, mfma 16x16x32) +
//  (a) B-stationary block order: bm fastest within XCD chunk (B-tile L2-reuse,
//      A panel streams through L3)
//  (b) T2-analog LDS swizzle: 16B chunk ^= (row&7), applied on BOTH sides
//      (pre-swizzled global source for linear global_load_lds dest + swizzled
//      ds_read addr) per rule #21 / m173.
// Requires M%128==0, N%128==0, K%64==0, grid%8==0 (all hold here).
template<int OUTBF16>
__global__ __launch_bounds__(256) void gemm_bt_k(
    const unsigned short* __restrict__ A, const unsigned short* __restrict__ B,
    void* __restrict__ Cout, int M, int N, int K)
{
    __shared__ __align__(16) unsigned short As[128 * 64];
    __shared__ __align__(16) unsigned short Bs[128 * 64];

    const int tid = threadIdx.x;
    const int w = tid >> 6, lane = tid & 63;
    const int nbm = M >> 7, nbn = N >> 7;
    const int cpx = (nbm * nbn) >> 3;            // grid % 8 == 0 -> bijective
    int swz = ((int)blockIdx.x & 7) * cpx + ((int)blockIdx.x >> 3);
    const int bm = swz % nbm, bn = swz / nbm;    // bm fastest: B-tile stationary

    const long ldK = K;
    // staging: thread t stages row (t>>3), 16B chunk (t&7) of the 32-row slab;
    // source column pre-swizzled by row&7 so that LDS[r][c] = G[r][c ^ (r&7)]
    const int srow = tid >> 3;
    const int scol = ((tid & 7) ^ (srow & 7)) * 8;
    const unsigned short* ga = A + ((long)(bm * 128 + srow)) * ldK + scol;
    const unsigned short* gb = B + ((long)(bn * 128 + srow)) * ldK + scol;

    const int wr = (w >> 1) * 64, wc = (w & 1) * 64;   // wave's 64x64 sub-tile
    const int lrow = lane & 15;
    const int hi = lane >> 4;                          // k-chunk sub-index
    const int rsw = lrow & 7;                          // read-side swizzle key

    f32x4 acc[4][4];
    #pragma unroll
    for (int m = 0; m < 4; ++m) {
        #pragma unroll
        for (int n = 0; n < 4; ++n) acc[m][n] = f32x4{0.f, 0.f, 0.f, 0.f};
    }

    const int nkt = K >> 6;
    for (int kt = 0; kt < nkt; ++kt) {
        #pragma unroll
        for (int j = 0; j < 4; ++j) {
            __builtin_amdgcn_global_load_lds((gptr_t)(ga + (long)j * 32 * ldK),
                (lptr_t)((char*)As + j * 4096 + w * 1024), 16, 0, 0);
            __builtin_amdgcn_global_load_lds((gptr_t)(gb + (long)j * 32 * ldK),
                (lptr_t)((char*)Bs + j * 4096 + w * 1024), 16, 0, 0);
        }
        ga += 64; gb += 64;
        __syncthreads();                                // drains vmcnt -> LDS ready
        #pragma unroll
        for (int ks = 0; ks < 2; ++ks) {
            bf16x8 fa[4], fb[4];
            const int kc = ((ks * 4 + hi) ^ rsw) << 3;  // swizzled k-chunk (elems)
            #pragma unroll
            for (int m = 0; m < 4; ++m)
                fa[m] = *(const bf16x8*)(&As[(wr + m * 16 + lrow) * 64 + kc]);
            #pragma unroll
            for (int n = 0; n < 4; ++n)
                fb[n] = *(const bf16x8*)(&Bs[(wc + n * 16 + lrow) * 64 + kc]);
            #pragma unroll
            for (int m = 0; m < 4; ++m) {
                #pragma unroll
                for (int n = 0; n < 4; ++n)
                    acc[m][n] = __builtin_amdgcn_mfma_f32_16x16x32_bf16(
                        fa[m], fb[n], acc[m][n], 0, 0, 0);
            }
        }
        __syncthreads();                                // protect LDS overwrite
    }

    // C/D layout (m89-verified): col = lane&15, row = (lane>>4)*4 + reg
    const int grow = bm * 128 + wr + hi * 4;
    const int gcol = bn * 128 + wc + lrow;
    if (OUTBF16) {
        unsigned short* C = (unsigned short*)Cout;
        #pragma unroll
        for (int m = 0; m < 4; ++m)
            #pragma unroll
            for (int n = 0; n < 4; ++n)
                #pragma unroll
                for (int r = 0; r < 4; ++r)
                    C[(long)(grow + m * 16 + r) * N + gcol + n * 16] = f2bf(acc[m][n][r]);
    } else {
        float* C = (float*)Cout;
        #pragma unroll
        for (int m = 0; m < 4; ++m)
            #pragma unroll
            for (int n = 0; n < 4; ++n)
                #pragma unroll
                for (int r = 0; r < 4; ++r)
                    C[(long)(grow + m * 16 + r) * N + gcol + n * 16] = acc[m][n][r];
    }
}

// ---- workspace layout (bytes) ----
//  [0)          W1 bf16 (90,177,536)  -- later reused for W2
//  [90177536)   W3 bf16 (90,177,536)
//  [180355072)  x  bf16 (33,554,432)
//  [213909504)  h1 bf16 (90,177,536)  -- swiglu output written in-place
//  [304087040)  h3 bf16 (90,177,536)
//  total 394,264,576
#define WS_NEEDED 394264576UL

extern "C" void kernel_launch(void* const* d_in, const int* in_sizes, int n_in,
                              void* d_out, int out_size, void* d_ws, size_t ws_size,
                              hipStream_t stream) {
    const float* x   = (const float*)d_in[0];
    const int*   w1c = (const int*)d_in[1];
    const float* w1a = (const float*)d_in[2];
    const int*   w2c = (const int*)d_in[3];
    const float* w2a = (const float*)d_in[4];
    const int*   w3c = (const int*)d_in[5];
    const float* w3a = (const float*)d_in[6];

    if (ws_size < WS_NEEDED) return;   // fail loudly via validation

    char* ws = (char*)d_ws;
    unsigned short* W1 = (unsigned short*)(ws);              // also W2 later
    unsigned short* W3 = (unsigned short*)(ws + 90177536);
    unsigned short* Xb = (unsigned short*)(ws + 180355072);
    unsigned short* H1 = (unsigned short*)(ws + 213909504);
    unsigned short* H3 = (unsigned short*)(ws + 304087040);

    const int wblk = NELW / (8 * 256);          // 22016
    dequant_nf4_k<<<wblk, 256, 0, stream>>>(w1c, w1a, W1);
    dequant_nf4_k<<<wblk, 256, 0, stream>>>(w3c, w3a, W3);
    cast_f32_bf16_k<<<(MTOK * DIM) / (8 * 256), 256, 0, stream>>>(x, Xb);

    // h1 = x @ W1^T, h3 = x @ W3^T   [4096 x 11008]
    gemm_bt_k<1><<<(MTOK / 128) * (HID / 128), 256, 0, stream>>>(Xb, W1, H1, MTOK, HID, DIM);
    gemm_bt_k<1><<<(MTOK / 128) * (HID / 128), 256, 0, stream>>>(Xb, W3, H3, MTOK, HID, DIM);

    // h = silu(h1) * h3, in-place into H1
    swiglu_k<<<wblk, 256, 0, stream>>>(H1, H3, H1);

    // W2 into W1's buffer (GEMM1 already retired on this stream)
    dequant_nf4_k<<<wblk, 256, 0, stream>>>(w2c, w2a, W1);

    // out = h @ W2^T  [4096 x 4096], fp32 output
    gemm_bt_k<0><<<(MTOK / 128) * (DIM / 128), 256, 0, stream>>>(H1, W1, (float*)d_out, MTOK, DIM, HID);
}

// Round 4
// 1164.523 us; speedup vs baseline: 1.5985x; 1.3617x over previous
//
#include <hip/hip_runtime.h>
#include <hip/hip_bf16.h>
#include <stdint.h>

// ---- problem dims (fixed by setup_inputs) ----
#define DIM   4096
#define HID   11008
#define MTOK  4096              // B*S = 2*2048
#define NELW  (HID * DIM)       // 45,088,768 elements per weight matrix

typedef __bf16 bf16x8 __attribute__((ext_vector_type(8)));
typedef float  f32x4  __attribute__((ext_vector_type(4)));
using gptr_t = const __attribute__((address_space(1))) void*;
using lptr_t = __attribute__((address_space(3))) void*;

__device__ __forceinline__ float bf2f(unsigned short u) {
    unsigned int t = ((unsigned int)u) << 16;
    float f; __builtin_memcpy(&f, &t, 4); return f;
}
__device__ __forceinline__ unsigned short f2bf(float f) {   // RNE
    unsigned int x; __builtin_memcpy(&x, &f, 4);
    x += 0x7fffu + ((x >> 16) & 1u);
    return (unsigned short)(x >> 16);
}

__device__ __constant__ float NF4_TAB[16] = {
    -1.0f, -0.6961928009986877f, -0.5250730514526367f, -0.39491748809814453f,
    -0.28444138169288635f, -0.18477343022823334f, -0.09105003625154495f, 0.0f,
    0.07958029955625534f, 0.16093020141124725f, 0.24611230194568634f,
    0.33791524171829224f, 0.44070982933044434f, 0.5626170039176941f,
    0.6989939212799072f, 1.0f};

// NF4 dequant: 8 codes/thread; table lookup via __shfl from lanes 0..15.
__global__ __launch_bounds__(256) void dequant_nf4_k(
    const int* __restrict__ codes, const float* __restrict__ absmax,
    unsigned short* __restrict__ out)
{
    long base = ((long)blockIdx.x * 256 + threadIdx.x) * 8;
    float tv = NF4_TAB[threadIdx.x & 15];           // lanes 0..15 hold the table
    int4 c0 = *(const int4*)(codes + base);
    int4 c1 = *(const int4*)(codes + base + 4);
    float s = absmax[base >> 6];
    union { uint4 q; unsigned short u[8]; } o;
    o.u[0] = f2bf(__shfl(tv, c0.x) * s);
    o.u[1] = f2bf(__shfl(tv, c0.y) * s);
    o.u[2] = f2bf(__shfl(tv, c0.z) * s);
    o.u[3] = f2bf(__shfl(tv, c0.w) * s);
    o.u[4] = f2bf(__shfl(tv, c1.x) * s);
    o.u[5] = f2bf(__shfl(tv, c1.y) * s);
    o.u[6] = f2bf(__shfl(tv, c1.z) * s);
    o.u[7] = f2bf(__shfl(tv, c1.w) * s);
    *(uint4*)(out + base) = o.q;
}

__global__ __launch_bounds__(256) void cast_f32_bf16_k(
    const float* __restrict__ in, unsigned short* __restrict__ out)
{
    long base = ((long)blockIdx.x * 256 + threadIdx.x) * 8;
    float4 a = *(const float4*)(in + base);
    float4 b = *(const float4*)(in + base + 4);
    union { uint4 q; unsigned short u[8]; } o;
    o.u[0] = f2bf(a.x); o.u[1] = f2bf(a.y); o.u[2] = f2bf(a.z); o.u[3] = f2bf(a.w);
    o.u[4] = f2bf(b.x); o.u[5] = f2bf(b.y); o.u[6] = f2bf(b.z); o.u[7] = f2bf(b.w);
    *(uint4*)(out + base) = o.q;
}

// ============================================================================
// 256x256-tile 4-phase/K-tile GEMM (plain-HIP port of the m201/HK schedule).
// C[m,n] = sum_k A[m,k]*B[n,k]; A:[M,K] bf16, B:[N,K] bf16 row-major.
// 512 thr = 8 waves (2M x 4N); BK=64; LDS = 2buf x {A,B} x 2half x [128][64]
// bf16 = 128 KiB.
//
// vmcnt LEDGER (verified r3 post-mortem; per-wave, 2 loads per STAGE):
//   prologue issues 12 (tile0 A0,A1,B0,B1 + tile1 A0,A1); vmcnt(4)+BAR
//     publishes tile0 entirely.  All LDS reads occur only AFTER a barrier
//     that every wave reached after its covering vmcnt (r3's NaN was the
//     prologue LDA sitting before that barrier).
//   iter t issues: ph1 B0[t+1]->nb, ph2 B1[t+1]->nb, ph3 A0[t+2]->cur,
//     ph4 A1[t+2]->cur.  ph3 vmcnt(6) => landed through A1[t+1] (publishes
//     A[t+1], read at ph4 + next ph2).  ph4 vmcnt(4) => landed through
//     B1[t+1] (publishes B[t+1], read at next ph1/ph3).  In-flight never
//     drops below 4 (T4).  Region overwrites: every STAGE's destination had
//     its last ds_read drained (consuming MFMA's lgkmcnt) before the barrier
//     preceding the STAGE issue.  Tail: tA clamps to NT-1; dupes land in the
//     dead opposite buffer.
// MODE: 0 = f32 out, 1 = bf16 out, 2 = bf16 fused h=silu(Cout)*acc in-place.
// Requires M%256==0, N%256==0, K%64==0, K>=128, grid%8==0 (all hold here).
// ============================================================================
template<int MODE>
__global__ __launch_bounds__(512, 2) void gemm256_k(
    const unsigned short* __restrict__ A, const unsigned short* __restrict__ B,
    void* __restrict__ Cout, int M, int N, int K)
{
    __shared__ __align__(16) unsigned short lds[2][2][2][128 * 64];

    const int tid = threadIdx.x;
    const int w = tid >> 6, lane = tid & 63;
    const int wm = w >> 2, wn = w & 3;           // 2M x 4N wave grid
    const int lrow = lane & 15, hi = lane >> 4;
    const int key = lrow & 7;                    // read-side swizzle key

    const int nbm = M >> 8, nbn = N >> 8;
    const int cpx = (nbm * nbn) >> 3;            // grid%8==0 -> bijective
    int swz = ((int)blockIdx.x & 7) * cpx + ((int)blockIdx.x >> 3);
    const int bm = swz % nbm, bn = swz / nbm;    // bm fastest: B-panel reuse

    const long ldK = K;
    const int srow = tid >> 3;                   // 0..63 staging row
    const int scol = ((tid & 7) ^ (srow & 7)) * 8;   // pre-swizzled source col
    const unsigned short* gA = A + ((long)(bm * 256 + srow)) * ldK + scol;
    const unsigned short* gB = B + ((long)(bn * 256 + srow)) * ldK + scol;

    f32x4 acc[8][4];
    #pragma unroll
    for (int m = 0; m < 8; ++m)
        #pragma unroll
        for (int n = 0; n < 4; ++n) acc[m][n] = f32x4{0.f, 0.f, 0.f, 0.f};

    bf16x8 a0[4][2], a1[4][2], b0[2][2], b1[2][2];

    // stage half-tile h (0=A rows0-127, 1=A rows128-255, 2=B0, 3=B1) of K-tile
    // kt into buffer b.  Linear LDS dest (wave-uniform base + lane*16).
    auto STAGE = [&](int kt, int h, int b) {
        const unsigned short* src = ((h >> 1) ? gB : gA)
            + (long)((h & 1) * 128) * ldK + (long)kt * 64;
        char* dst = (char*)&lds[b][h >> 1][h & 1][0] + w * 1024;
        __builtin_amdgcn_global_load_lds((gptr_t)src, (lptr_t)dst, 16, 0, 0);
        __builtin_amdgcn_global_load_lds((gptr_t)(src + (long)64 * ldK),
                                         (lptr_t)(dst + 8192), 16, 0, 0);
    };
    // lane's A fragments: which=0 -> rows 0-63 of wave's half, 1 -> rows 64-127
    auto LDA = [&](bf16x8 (&fr)[4][2], int which, int b) {
        const unsigned short* base = &lds[b][0][wm][0];
        #pragma unroll
        for (int m = 0; m < 4; ++m)
            #pragma unroll
            for (int ks = 0; ks < 2; ++ks)
                fr[m][ks] = *(const bf16x8*)(base + (which * 64 + m * 16 + lrow) * 64
                                             + (((ks * 4 + hi) ^ key) * 8));
    };
    // lane's B fragments: which=0 -> n0..1, 1 -> n2..3
    auto LDB = [&](bf16x8 (&fr)[2][2], int which, int b) {
        const unsigned short* base = &lds[b][1][wn >> 1][0];
        #pragma unroll
        for (int n = 0; n < 2; ++n)
            #pragma unroll
            for (int ks = 0; ks < 2; ++ks)
                fr[n][ks] = *(const bf16x8*)(base + ((wn & 1) * 64 + (which * 2 + n) * 16 + lrow) * 64
                                             + (((ks * 4 + hi) ^ key) * 8));
    };
    auto MMA = [&](bf16x8 (&fa)[4][2], bf16x8 (&fb)[2][2], int mo, int no) {
        __builtin_amdgcn_s_setprio(1);
        #pragma unroll
        for (int m = 0; m < 4; ++m)
            #pragma unroll
            for (int n = 0; n < 2; ++n)
                #pragma unroll
                for (int ks = 0; ks < 2; ++ks)
                    acc[mo + m][no + n] = __builtin_amdgcn_mfma_f32_16x16x32_bf16(
                        fa[m][ks], fb[n][ks], acc[mo + m][no + n], 0, 0, 0);
        __builtin_amdgcn_s_setprio(0);
    };
    #define BAR() do { __builtin_amdgcn_s_barrier(); \
                       __builtin_amdgcn_sched_barrier(0); } while (0)

    const int NT = K >> 6;
    // ---- prologue: tile0 fully + A-halves of tile1; publish tile0, THEN read
    STAGE(0, 0, 0); STAGE(0, 1, 0); STAGE(0, 2, 0); STAGE(0, 3, 0);
    STAGE(1, 0, 1); STAGE(1, 1, 1);
    asm volatile("s_waitcnt vmcnt(4)" ::: "memory");   // own tile0 loads landed
    BAR();                                             // ...and everyone else's
    LDA(a0, 0, 0);                                     // r3 fix: read AFTER bar

    int cur = 0;
    for (int t = 0; t < NT - 1; ++t) {
        const int nb = cur ^ 1;
        const int tA = (t + 2 < NT) ? t + 2 : NT - 1;  // clamped: dupes land dead
        // ph1: B[t] lower frags; issue B0[t+1]
        STAGE(t + 1, 2, nb);
        LDB(b0, 0, cur);
        BAR();
        MMA(a0, b0, 0, 0);
        BAR();
        // ph2: A[t] upper frags; issue B1[t+1]
        STAGE(t + 1, 3, nb);
        LDA(a1, 1, cur);
        BAR();
        MMA(a1, b0, 4, 0);
        BAR();
        // ph3: B[t] upper frags; issue A0[t+2]; publish A[t+1] (vmcnt 6)
        STAGE(tA, 0, cur);
        LDB(b1, 1, cur);
        BAR();
        MMA(a0, b1, 0, 2);
        asm volatile("s_waitcnt vmcnt(6)" ::: "memory");
        BAR();
        // ph4: A[t+1] lower frags from next buf; issue A1[t+2]; publish B[t+1]
        STAGE(tA, 1, cur);
        LDA(a0, 0, nb);
        BAR();
        MMA(a1, b1, 4, 2);
        asm volatile("s_waitcnt vmcnt(4)" ::: "memory");
        BAR();
        cur = nb;
    }
    // ---- epilogue: last tile, fully published by final ph3/ph4 waits ----
    LDB(b0, 0, cur);
    MMA(a0, b0, 0, 0);
    LDA(a1, 1, cur);
    MMA(a1, b0, 4, 0);
    LDB(b1, 1, cur);
    MMA(a0, b1, 0, 2);
    MMA(a1, b1, 4, 2);
    #undef BAR

    // ---- C write.  C/D layout: col = lane&15, row = (lane>>4)*4 + reg ----
    const int grow = bm * 256 + wm * 128 + hi * 4;
    const int gcol = bn * 256 + wn * 64 + lrow;
    if (MODE == 0) {
        float* C = (float*)Cout;
        #pragma unroll
        for (int m = 0; m < 8; ++m)
            #pragma unroll
            for (int n = 0; n < 4; ++n)
                #pragma unroll
                for (int r = 0; r < 4; ++r)
                    C[(long)(grow + m * 16 + r) * N + gcol + n * 16] = acc[m][n][r];
    } else if (MODE == 1) {
        unsigned short* C = (unsigned short*)Cout;
        #pragma unroll
        for (int m = 0; m < 8; ++m)
            #pragma unroll
            for (int n = 0; n < 4; ++n)
                #pragma unroll
                for (int r = 0; r < 4; ++r)
                    C[(long)(grow + m * 16 + r) * N + gcol + n * 16] = f2bf(acc[m][n][r]);
    } else {
        // fused SwiGLU: C holds h1 (bf16); acc = h3. write silu(h1)*h3 in place
        unsigned short* C = (unsigned short*)Cout;
        #pragma unroll
        for (int m = 0; m < 8; ++m)
            #pragma unroll
            for (int n = 0; n < 4; ++n)
                #pragma unroll
                for (int r = 0; r < 4; ++r) {
                    long idx = (long)(grow + m * 16 + r) * N + gcol + n * 16;
                    float h1v = bf2f(C[idx]);
                    float g = h1v / (1.0f + __expf(-h1v));
                    C[idx] = f2bf(g * acc[m][n][r]);
                }
    }
}

// ---- workspace layout (bytes) ----
//  [0)          W1 bf16 (90,177,536)  -- later reused for W2
//  [90177536)   W3 bf16 (90,177,536)
//  [180355072)  x  bf16 (33,554,432)
//  [213909504)  h1 bf16 (90,177,536)  -- fused swiglu written in-place by GEMM2
//  total 304,087,040
#define WS_NEEDED 304087040UL

extern "C" void kernel_launch(void* const* d_in, const int* in_sizes, int n_in,
                              void* d_out, int out_size, void* d_ws, size_t ws_size,
                              hipStream_t stream) {
    const float* x   = (const float*)d_in[0];
    const int*   w1c = (const int*)d_in[1];
    const float* w1a = (const float*)d_in[2];
    const int*   w2c = (const int*)d_in[3];
    const float* w2a = (const float*)d_in[4];
    const int*   w3c = (const int*)d_in[5];
    const float* w3a = (const float*)d_in[6];

    if (ws_size < WS_NEEDED) return;   // fail loudly via validation

    char* ws = (char*)d_ws;
    unsigned short* W1 = (unsigned short*)(ws);              // also W2 later
    unsigned short* W3 = (unsigned short*)(ws + 90177536);
    unsigned short* Xb = (unsigned short*)(ws + 180355072);
    unsigned short* H1 = (unsigned short*)(ws + 213909504);

    const int wblk = NELW / (8 * 256);          // 22016
    dequant_nf4_k<<<wblk, 256, 0, stream>>>(w1c, w1a, W1);
    dequant_nf4_k<<<wblk, 256, 0, stream>>>(w3c, w3a, W3);
    cast_f32_bf16_k<<<(MTOK * DIM) / (8 * 256), 256, 0, stream>>>(x, Xb);

    // h1 = x @ W1^T  [4096 x 11008] bf16
    gemm256_k<1><<<(MTOK / 256) * (HID / 256), 512, 0, stream>>>(Xb, W1, H1, MTOK, HID, DIM);
    // h  = silu(h1) * (x @ W3^T), fused epilogue, in-place into H1
    gemm256_k<2><<<(MTOK / 256) * (HID / 256), 512, 0, stream>>>(Xb, W3, H1, MTOK, HID, DIM);

    // W2 into W1's buffer (GEMM1 retired; GEMM2 reads only W3/Xb/H1)
    dequant_nf4_k<<<wblk, 256, 0, stream>>>(w2c, w2a, W1);

    // out = h @ W2^T  [4096 x 4096], fp32 output
    gemm256_k<0><<<(MTOK / 256) * (DIM / 256), 512, 0, stream>>>(H1, W1, (float*)d_out, MTOK, DIM, HID);
}